// Round 1
// baseline (1895.959 us; speedup 1.0000x reference)
//
#include <hip/hip_runtime.h>
#include <hip/hip_bf16.h>
#include <math.h>

#define B_ 8
#define T_ 12
#define N_ 200
#define H_ 64
#define D_ 32
#define GIN_ 198

__device__ __forceinline__ float sigm(float v) { return 1.f / (1.f + expf(-v)); }

// ---------------- init: state = 0, state_dy = nf @ Ws2d + b ----------------
__global__ void k_init(const float* __restrict__ nf, const float* __restrict__ Ws2d,
                       const float* __restrict__ bs2d,
                       float* __restrict__ state, float* __restrict__ state_dy) {
    int row = blockIdx.x;            // b*N + n
    int n = row % N_;
    int o = threadIdx.x;             // 0..63
    state[row * H_ + o] = 0.f;
    if (o < D_) {
        float acc = bs2d[o];
        for (int i = 0; i < 64; ++i) acc += nf[n * 64 + i] * Ws2d[i * D_ + o];
        state_dy[row * D_ + o] = acc;
    }
}

// ---------------- dy-GRU + P/Q precompute, one block (64 thr) per row ------
__global__ void k_dygru(const float* __restrict__ x, int t,
                        const float* __restrict__ Wrz, const float* __restrict__ brz,
                        const float* __restrict__ Wh,  const float* __restrict__ bh,
                        const float* __restrict__ Wc2, const float* __restrict__ Wm2,
                        float* __restrict__ state_dy,
                        float* __restrict__ Pc, float* __restrict__ Qc,
                        float* __restrict__ Pm, float* __restrict__ Qm) {
    __shared__ float in1[33], rz[64], in2[33], s_sh[32];
    int row = blockIdx.x;
    int b = row / N_, n = row % N_;
    int o = threadIdx.x;
    if (o == 0) { float v = x[((b * T_ + t) * N_ + n) * 2 + 0]; in1[0] = v; in2[0] = v; }
    if (o >= 1 && o < 33) in1[o] = state_dy[row * D_ + o - 1];
    __syncthreads();
    float acc = brz[o];
    #pragma unroll
    for (int i = 0; i < 33; ++i) acc += in1[i] * Wrz[i * 64 + o];
    rz[o] = sigm(acc);
    __syncthreads();
    if (o >= 1 && o < 33) in2[o] = rz[o - 1] * in1[o];
    __syncthreads();
    if (o < D_) {
        float h = bh[o];
        #pragma unroll
        for (int i = 0; i < 33; ++i) h += in2[i] * Wh[i * D_ + o];
        h = tanhf(h);
        float z = rz[D_ + o];
        float nd = z * in1[o + 1] + (1.f - z) * h;
        state_dy[row * D_ + o] = nd;
        s_sh[o] = nd > 0.f ? nd : 0.f;
    }
    __syncthreads();
    for (int idx = o; idx < 128; idx += 64) {
        int mat = idx >> 5, k = idx & 31;
        const float* W = (mat < 2) ? Wc2 : Wm2;
        int base = (mat & 1) ? D_ : 0;      // Q uses rows 32..63
        float a = 0.f;
        #pragma unroll
        for (int i = 0; i < D_; ++i) a += s_sh[i] * W[(base + i) * D_ + k];
        float* dst = (mat == 0) ? Pc : (mat == 1) ? Qc : (mat == 2) ? Pm : Qm;
        dst[row * D_ + k] = a;
    }
}

// ---------------- pair MLP: A[b,i,j] = g * sigmoid(m) ----------------------
__global__ void k_pair(const float* __restrict__ Pc, const float* __restrict__ Qc,
                       const float* __restrict__ Pm, const float* __restrict__ Qm,
                       const float* __restrict__ bc2, const float* __restrict__ Wc1,
                       const float* __restrict__ bc1,
                       const float* __restrict__ bm2, const float* __restrict__ Wm1,
                       const float* __restrict__ bm1,
                       float* __restrict__ Aout) {
    __shared__ float sPc[16][33], sQc[16][33], sPm[16][33], sQm[16][33];
    __shared__ float sbc2[32], sWc1[32], sbm2[32], sWm1[32];
    int b = blockIdx.z;
    int i0 = blockIdx.x * 16, j0 = blockIdx.y * 16;
    int tid = threadIdx.y * 16 + threadIdx.x;
    for (int l = tid; l < 512; l += 256) {
        int r = l >> 5, k = l & 31;
        int gi = i0 + r, gj = j0 + r;
        sPc[r][k] = (gi < N_) ? Pc[(b * N_ + gi) * D_ + k] : 0.f;
        sPm[r][k] = (gi < N_) ? Pm[(b * N_ + gi) * D_ + k] : 0.f;
        sQc[r][k] = (gj < N_) ? Qc[(b * N_ + gj) * D_ + k] : 0.f;
        sQm[r][k] = (gj < N_) ? Qm[(b * N_ + gj) * D_ + k] : 0.f;
    }
    if (tid < 32) { sbc2[tid] = bc2[tid]; sWc1[tid] = Wc1[tid];
                    sbm2[tid] = bm2[tid]; sWm1[tid] = Wm1[tid]; }
    __syncthreads();
    int i = i0 + threadIdx.y, j = j0 + threadIdx.x;
    if (i >= N_ || j >= N_) return;
    float g = 0.f, m = 0.f;
    #pragma unroll
    for (int k = 0; k < 32; ++k) {
        float hc = sPc[threadIdx.y][k] + sQc[threadIdx.x][k] + sbc2[k];
        g += (hc > 0.f ? hc : 0.f) * sWc1[k];
        float hm = sPm[threadIdx.y][k] + sQm[threadIdx.x][k] + sbm2[k];
        m += (hm > 0.f ? hm : 0.f) * sWm1[k];
    }
    g += bc1[0];
    m += bm1[0];
    Aout[(b * N_ + i) * N_ + j] = g * sigm(m);
}

// ---------------- spmm hop1: out = A @ concat(xt, S) -----------------------
__global__ void k_spmm_concat(const float* __restrict__ A, const float* __restrict__ x,
                              int t, const float* __restrict__ S, float* __restrict__ out) {
    __shared__ float arow[N_];
    int row = blockIdx.x;
    int b = row / N_, i = row % N_;
    int tid = threadIdx.x;
    for (int j = tid; j < N_; j += 64) arow[j] = A[(b * N_ + i) * N_ + j];
    __syncthreads();
    for (int c = tid; c < 66; c += 64) {
        float acc = 0.f;
        if (c < 2) {
            for (int j = 0; j < N_; ++j) acc += arow[j] * x[((b * T_ + t) * N_ + j) * 2 + c];
        } else {
            #pragma unroll 4
            for (int j = 0; j < N_; ++j) acc += arow[j] * S[(b * N_ + j) * H_ + (c - 2)];
        }
        out[row * 66 + c] = acc;
    }
}

// ---------------- spmm hop2: out = A @ X (X is B,N,66) ---------------------
__global__ void k_spmm_plain(const float* __restrict__ A, const float* __restrict__ X,
                             float* __restrict__ out) {
    __shared__ float arow[N_];
    int row = blockIdx.x;
    int b = row / N_, i = row % N_;
    int tid = threadIdx.x;
    for (int j = tid; j < N_; j += 64) arow[j] = A[(b * N_ + i) * N_ + j];
    __syncthreads();
    for (int c = tid; c < 66; c += 64) {
        float acc = 0.f;
        #pragma unroll 4
        for (int j = 0; j < N_; ++j) acc += arow[j] * X[(b * N_ + j) * 66 + c];
        out[row * 66 + c] = acc;
    }
}

// ---------------- ru = sigmoid(feats @ W_ru + b); emit u, rs=rr*state ------
__global__ void k_ru(const float* __restrict__ x, int t, const float* __restrict__ state,
                     const float* __restrict__ x1, const float* __restrict__ x2,
                     const float* __restrict__ Wru, const float* __restrict__ bru,
                     float* __restrict__ u_ws, float* __restrict__ rs_ws) {
    __shared__ float f[GIN_];
    int row = blockIdx.x;
    int b = row / N_, n = row % N_;
    int tid = threadIdx.x;               // 0..127
    for (int l = tid; l < GIN_; l += 128) {
        float v;
        if (l < 2)        v = x[((b * T_ + t) * N_ + n) * 2 + l];
        else if (l < 66)  v = state[row * H_ + l - 2];
        else if (l < 132) v = x1[row * 66 + l - 66];
        else              v = x2[row * 66 + l - 132];
        f[l] = v;
    }
    __syncthreads();
    float acc = bru[tid];
    #pragma unroll 6
    for (int i = 0; i < GIN_; ++i) acc += f[i] * Wru[i * 128 + tid];
    float v = sigm(acc);
    if (tid < H_) rs_ws[row * H_ + tid] = v * state[row * H_ + tid];
    else          u_ws[row * H_ + tid - H_] = v;
}

// ---------------- c = tanh(feats_c @ W_cand + b); state update -------------
__global__ void k_cand(const float* __restrict__ x, int t, const float* __restrict__ rs,
                       const float* __restrict__ x1, const float* __restrict__ x2,
                       const float* __restrict__ Wc, const float* __restrict__ bc,
                       const float* __restrict__ u_ws, float* __restrict__ state) {
    __shared__ float f[GIN_];
    int row = blockIdx.x;
    int b = row / N_, n = row % N_;
    int tid = threadIdx.x;               // 0..63
    for (int l = tid; l < GIN_; l += 64) {
        float v;
        if (l < 2)        v = x[((b * T_ + t) * N_ + n) * 2 + l];
        else if (l < 66)  v = rs[row * H_ + l - 2];
        else if (l < 132) v = x1[row * 66 + l - 66];
        else              v = x2[row * 66 + l - 132];
        f[l] = v;
    }
    __syncthreads();
    float acc = bc[tid];
    #pragma unroll 6
    for (int i = 0; i < GIN_; ++i) acc += f[i] * Wc[i * H_ + tid];
    float c = tanhf(acc);
    float u = u_ws[row * H_ + tid];
    float st = state[row * H_ + tid];
    state[row * H_ + tid] = u * st + (1.f - u) * c;
}

// ---------------- pred head ------------------------------------------------
__global__ void k_pred(const float* __restrict__ state,
                       const float* __restrict__ Wp1, const float* __restrict__ bp1,
                       const float* __restrict__ Wp2, const float* __restrict__ bp2,
                       float* __restrict__ out) {
    __shared__ float st[H_];
    int row = blockIdx.x;
    int tid = threadIdx.x;               // 0..63, one wave
    st[tid] = state[row * H_ + tid];
    __syncthreads();
    float acc = bp1[tid];
    #pragma unroll
    for (int a = 0; a < H_; ++a) acc += st[a] * Wp1[a * H_ + tid];
    acc = acc > 0.f ? acc : 0.01f * acc;      // leaky_relu default slope
    float v = acc * Wp2[tid];
    #pragma unroll
    for (int off = 32; off > 0; off >>= 1) v += __shfl_down(v, off);
    if (tid == 0) out[row] = v + bp2[0];
}

extern "C" void kernel_launch(void* const* d_in, const int* in_sizes, int n_in,
                              void* d_out, int out_size, void* d_ws, size_t ws_size,
                              hipStream_t stream) {
    const float* x    = (const float*)d_in[0];
    const float* nf   = (const float*)d_in[1];
    const float* Ws2d = (const float*)d_in[2];
    const float* bs2d = (const float*)d_in[3];
    const float* Wrz  = (const float*)d_in[4];
    const float* brz  = (const float*)d_in[5];
    const float* Wh   = (const float*)d_in[6];
    const float* bh   = (const float*)d_in[7];
    const float* Wc2  = (const float*)d_in[8];
    const float* bc2  = (const float*)d_in[9];
    const float* Wc1  = (const float*)d_in[10];
    const float* bc1  = (const float*)d_in[11];
    const float* Wm2  = (const float*)d_in[12];
    const float* bm2  = (const float*)d_in[13];
    const float* Wm1  = (const float*)d_in[14];
    const float* bm1  = (const float*)d_in[15];
    const float* Wru  = (const float*)d_in[16];
    const float* bru  = (const float*)d_in[17];
    const float* Wcand= (const float*)d_in[18];
    const float* bcand= (const float*)d_in[19];
    const float* Wp1  = (const float*)d_in[20];
    const float* bp1  = (const float*)d_in[21];
    const float* Wp2  = (const float*)d_in[22];
    const float* bp2  = (const float*)d_in[23];
    float* out = (float*)d_out;

    const int R = B_ * N_;               // 1600 rows
    float* ws = (float*)d_ws;
    float* state    = ws;                // R*64
    float* state_dy = state + R * 64;    // R*32
    float* Pc = state_dy + R * 32;       // R*32
    float* Qc = Pc + R * 32;             // R*32
    float* Pm = Qc + R * 32;             // R*32
    float* Qm = Pm + R * 32;             // R*32
    float* x1 = Qm + R * 32;             // R*66
    float* x2 = x1 + R * 66;             // R*66
    float* rs = x2 + R * 66;             // R*64
    float* ub = rs + R * 64;             // R*64
    // total ~825600 floats = 3.2 MB of ws

    k_init<<<R, 64, 0, stream>>>(nf, Ws2d, bs2d, state, state_dy);

    for (int t = 0; t < T_; ++t) {
        float* At = out + R + (size_t)t * B_ * N_ * N_;   // dy_graphs[t]
        k_dygru<<<R, 64, 0, stream>>>(x, t, Wrz, brz, Wh, bh, Wc2, Wm2,
                                      state_dy, Pc, Qc, Pm, Qm);
        k_pair<<<dim3(13, 13, B_), dim3(16, 16), 0, stream>>>(
            Pc, Qc, Pm, Qm, bc2, Wc1, bc1, bm2, Wm1, bm1, At);
        // ru path graph conv
        k_spmm_concat<<<R, 64, 0, stream>>>(At, x, t, state, x1);
        k_spmm_plain <<<R, 64, 0, stream>>>(At, x1, x2);
        k_ru<<<R, 128, 0, stream>>>(x, t, state, x1, x2, Wru, bru, ub, rs);
        // cand path graph conv (reuses x1/x2 buffers)
        k_spmm_concat<<<R, 64, 0, stream>>>(At, x, t, rs, x1);
        k_spmm_plain <<<R, 64, 0, stream>>>(At, x1, x2);
        k_cand<<<R, 64, 0, stream>>>(x, t, rs, x1, x2, Wcand, bcand, ub, state);
    }

    k_pred<<<R, 64, 0, stream>>>(state, Wp1, bp1, Wp2, bp2, out);
}